// Round 9
// baseline (203.542 us; speedup 1.0000x reference)
//
#include <hip/hip_runtime.h>
#include <hip/hip_bf16.h>
#include <math.h>

// Problem constants (B=2, C=256, H=W=128, N=16384, SR=4, HEADS=8, hd=32, M=1024)
#define EPSF 1e-5f
#define SCALE 0.17677669529663687f  // 1/sqrt(32)

typedef __bf16 bf16x8 __attribute__((ext_vector_type(8)));
typedef __bf16 bf16x4 __attribute__((ext_vector_type(4)));
typedef float f32x4 __attribute__((ext_vector_type(4)));

// Fragment-major layouts (MFMA 16x16x32, A/B frag = [row/col ln<16][k=quad*8+j]):
//   xTf : x^T  [b][n_tile(1024)][cc(8)][lane(64)][j(8)]
//   wqf : w_q  [o_tile(16)][cc(8)][lane][j]
//   Pbf : P    [b][m_tile(64)][cc(128)][lane][j]
//   wsrf: w_sr [o_tile(16)][cc(128)][lane][j]
//   kkbh: k    [b][h(8)][m(1024)][d(32)]
//   vpart: x row-sums [b][c][hm(32)]  (non-atomic partials, summed in k_kmat2)
//
// NOTE: cross-block result handoff (ssg -> out) goes through a KERNEL BOUNDARY
// (k_scores3 -> k_epi).  R8's in-kernel completion counter raced under the
// non-coherent per-XCD L2 model (post-timing absmax 0.56) — do not re-fuse.

// ---------------------------------------------------------------------------
// k_prep: ONE launch for all input staging.  1632 blocks:
//   0..575    weight conversions (wq->wqf, wk->wkb*SCALE, wsr->wsrf)
//   576..1087 im2col x->Pbf + vpart partial sums
//   1088..1599 x->xTf transpose
//   1600..1631 zero ssg
__global__ __launch_bounds__(256) void k_prep(const float* __restrict__ x,
                                              const float* __restrict__ wq,
                                              const float* __restrict__ wk,
                                              const float* __restrict__ wsr,
                                              __bf16* __restrict__ wqf,
                                              __bf16* __restrict__ wkb,
                                              __bf16* __restrict__ wsrf,
                                              __bf16* __restrict__ Pbf,
                                              __bf16* __restrict__ xTf,
                                              float* __restrict__ vpart,
                                              float* __restrict__ ssg) {
    int bi = blockIdx.x, t = threadIdx.x;
    if (bi < 32) {
        int tt = bi * 256 + t;
        int o = tt >> 5, chunk = tt & 31;
        float4 v0 = *(const float4*)&wq[o * 256 + (chunk << 3)];
        float4 v1 = *(const float4*)&wq[o * 256 + (chunk << 3) + 4];
        bf16x8 p;
        p[0] = (__bf16)v0.x; p[1] = (__bf16)v0.y; p[2] = (__bf16)v0.z; p[3] = (__bf16)v0.w;
        p[4] = (__bf16)v1.x; p[5] = (__bf16)v1.y; p[6] = (__bf16)v1.z; p[7] = (__bf16)v1.w;
        int cc = chunk >> 2, quad = chunk & 3;
        *(bf16x8*)&wqf[(((((o >> 4) << 3) + cc) << 6) + (quad << 4) + (o & 15)) << 3] = p;
    } else if (bi < 64) {
        int e = (bi - 32) * 256 + t;
        float4 v0 = *(const float4*)&wk[e << 3];
        float4 v1 = *(const float4*)&wk[(e << 3) + 4];
        bf16x8 p;
        p[0] = (__bf16)(v0.x * SCALE); p[1] = (__bf16)(v0.y * SCALE);
        p[2] = (__bf16)(v0.z * SCALE); p[3] = (__bf16)(v0.w * SCALE);
        p[4] = (__bf16)(v1.x * SCALE); p[5] = (__bf16)(v1.y * SCALE);
        p[6] = (__bf16)(v1.z * SCALE); p[7] = (__bf16)(v1.w * SCALE);
        *(bf16x8*)&wkb[e << 3] = p;
    } else if (bi < 576) {
        int tt = (bi - 64) * 256 + t;
        int o = tt >> 9, chunk = tt & 511;
        float4 v0 = *(const float4*)&wsr[o * 4096 + (chunk << 3)];
        float4 v1 = *(const float4*)&wsr[o * 4096 + (chunk << 3) + 4];
        bf16x8 p;
        p[0] = (__bf16)v0.x; p[1] = (__bf16)v0.y; p[2] = (__bf16)v0.z; p[3] = (__bf16)v0.w;
        p[4] = (__bf16)v1.x; p[5] = (__bf16)v1.y; p[6] = (__bf16)v1.z; p[7] = (__bf16)v1.w;
        int cc = chunk >> 2, quad = chunk & 3;
        *(bf16x8*)&wsrf[(((((o >> 4) << 7) + cc) << 6) + (quad << 4) + (o & 15)) << 3] = p;
    } else if (bi < 1088) {
        // ---- im2col + vpart ----
        __shared__ float csum[32];
        int bid = bi - 576;
        int b = bid >> 8, hm = (bid >> 3) & 31, ccg = bid & 7;
        int wm = t >> 3, c8 = t & 7;
        if (t < 32) csum[t] = 0.f;
        __syncthreads();
        const int mtile = (hm << 1) + (wm >> 4);
        const int ln = wm & 15;
#pragma unroll
        for (int cci = 0; cci < 4; ++cci) {
            int c = (ccg << 5) + (cci << 3) + c8;
            const float* src = x + ((size_t)(b * 256 + c) << 14) + (hm << 9) + (wm << 2);
            bf16x8 o0, o1;
            float s = 0.f;
#pragma unroll
            for (int p = 0; p < 2; ++p) {
                float4 vv = *(const float4*)&src[p << 7];
                s += vv.x + vv.y + vv.z + vv.w;
                o0[p * 4 + 0] = (__bf16)vv.x; o0[p * 4 + 1] = (__bf16)vv.y;
                o0[p * 4 + 2] = (__bf16)vv.z; o0[p * 4 + 3] = (__bf16)vv.w;
            }
#pragma unroll
            for (int p = 0; p < 2; ++p) {
                float4 vv = *(const float4*)&src[(p + 2) << 7];
                s += vv.x + vv.y + vv.z + vv.w;
                o1[p * 4 + 0] = (__bf16)vv.x; o1[p * 4 + 1] = (__bf16)vv.y;
                o1[p * 4 + 2] = (__bf16)vv.z; o1[p * 4 + 3] = (__bf16)vv.w;
            }
            size_t d0 = (((((size_t)(b * 64 + mtile) << 7) + (c >> 1)) << 6) +
                         (((c & 1) << 1) << 4) + ln) << 3;
            *(bf16x8*)&Pbf[d0] = o0;
            *(bf16x8*)&Pbf[d0 + 128] = o1;
            atomicAdd(&csum[(cci << 3) + c8], s);
        }
        __syncthreads();
        if (t < 32) vpart[((b * 256 + (ccg << 5) + t) << 5) + hm] = csum[t];
    } else if (bi < 1600) {
        // ---- xT transpose ----
        __shared__ float ts[32 * 68];
        int bid = bi - 1088;
        int b = bid >> 8, n0 = (bid & 255) << 6;
        const int nl = t >> 2;
        const int ch = (t & 3) << 3;
        const int n = n0 + nl;
        const int ntile = n >> 4, ln = n & 15, quad = ch >> 3;
        const int cl = t >> 3;
        const int n8 = (t & 7) << 3;
        for (int s8 = 0; s8 < 8; ++s8) {
            int c0 = s8 << 5;
            __syncthreads();
            {
                const float* src = &x[((size_t)(b * 256 + c0 + cl) << 14) + n0 + n8];
                *(float4*)&ts[cl * 68 + n8] = *(const float4*)&src[0];
                *(float4*)&ts[cl * 68 + n8 + 4] = *(const float4*)&src[4];
            }
            __syncthreads();
            bf16x8 p;
#pragma unroll
            for (int j = 0; j < 8; ++j) p[j] = (__bf16)ts[(ch + j) * 68 + nl];
            *(bf16x8*)&xTf[(((((size_t)(b * 1024 + ntile) << 3) + s8) << 6) +
                            (quad << 4) + ln) << 3] = p;
        }
    } else {
        int e = (bi - 1600) * 256 + t;
        *(float4*)&ssg[e << 2] = make_float4(0.f, 0.f, 0.f, 0.f);
    }
}

// ---------------------------------------------------------------------------
// k_conv1f: full-K MFMA GEMM + fused BN + bf16 store.  Dual accumulators.
// grid = b(2) * mt(64) * og(4) = 512; wave w handles otile og*4+w.
__global__ __launch_bounds__(256) void k_conv1f(const __bf16* __restrict__ Pbf,
                                                const __bf16* __restrict__ wsrf,
                                                const float* __restrict__ sg,
                                                const float* __restrict__ sb,
                                                const float* __restrict__ smn,
                                                const float* __restrict__ svar,
                                                __bf16* __restrict__ xrb) {
    const int t = threadIdx.x, bid = blockIdx.x;
    const int b = bid & 1, mt = (bid >> 1) & 63, og = bid >> 7;
    const int w = t >> 6, lane = t & 63, ln = lane & 15, quad = lane >> 4;
    f32x4 acc0 = (f32x4){0.f, 0.f, 0.f, 0.f};
    f32x4 acc1 = (f32x4){0.f, 0.f, 0.f, 0.f};
    const __bf16* pa = Pbf + ((size_t)(b * 64 + mt) << 16) + (lane << 3);
    const __bf16* pbm = wsrf + ((size_t)(og * 4 + w) << 16) + (lane << 3);
#pragma unroll 4
    for (int cc = 0; cc < 128; cc += 2) {
        bf16x8 a0 = *(const bf16x8*)&pa[cc << 9];
        bf16x8 b0 = *(const bf16x8*)&pbm[cc << 9];
        bf16x8 a1 = *(const bf16x8*)&pa[(cc + 1) << 9];
        bf16x8 b1 = *(const bf16x8*)&pbm[(cc + 1) << 9];
        acc0 = __builtin_amdgcn_mfma_f32_16x16x32_bf16(a0, b0, acc0, 0, 0, 0);
        acc1 = __builtin_amdgcn_mfma_f32_16x16x32_bf16(a1, b1, acc1, 0, 0, 0);
    }
    f32x4 acc = acc0 + acc1;
    const int o = (og << 6) + (w << 4) + ln;
    float inv = sg[o] / sqrtf(svar[o] + EPSF);
    float mn = smn[o], bt = sb[o];
#pragma unroll
    for (int r = 0; r < 4; ++r) {
        int m = (mt << 4) + (quad << 2) + r;
        xrb[(((size_t)b << 10) + m) * 256 + o] = (__bf16)((acc[r] - mn) * inv + bt);
    }
}

// ---------------------------------------------------------------------------
// k_kmat2: MFMA GEMM kkbh = xrb x wkb (blocks 0..127) + A/B0 epilogue consts
// (blocks 128..129, summing vpart).
__global__ __launch_bounds__(256) void k_kmat2(const __bf16* __restrict__ xrb,
                                               const __bf16* __restrict__ wkb,
                                               __bf16* __restrict__ kkbh,
                                               const float* __restrict__ vpart,
                                               const float* __restrict__ wproj,
                                               const float* __restrict__ pg,
                                               const float* __restrict__ pb,
                                               const float* __restrict__ pm,
                                               const float* __restrict__ pvar,
                                               float* __restrict__ A,
                                               float* __restrict__ B0) {
    const int t = threadIdx.x, bid = blockIdx.x;
    if (bid >= 128) {
        __shared__ float vl[256];
        int b = bid - 128;
        const float* vp = vpart + ((b * 256 + t) << 5);
        float s = 0.f;
#pragma unroll
        for (int j = 0; j < 32; j += 4) {
            float4 p4 = *(const float4*)&vp[j];
            s += p4.x + p4.y + p4.z + p4.w;
        }
        vl[t] = s * (1.0f / 16384.0f);
        __syncthreads();
        const float* wr = wproj + t * 256;
        float acc = 0.f;
#pragma unroll 8
        for (int c = 0; c < 256; c += 4) {
            float4 w4 = *(const float4*)&wr[c];
            acc += w4.x * vl[c] + w4.y * vl[c + 1] + w4.z * vl[c + 2] + w4.w * vl[c + 3];
        }
        float inv = pg[t] / sqrtf(pvar[t] + EPSF);
        A[b * 256 + t] = acc * inv;
        if (b == 0) B0[t] = pb[t] - pm[t] * inv;
        return;
    }
    const int b = bid >> 6, mt = bid & 63;
    const int w = t >> 6, lane = t & 63, ln = lane & 15, quad = lane >> 4;
    f32x4 acc[4];
#pragma unroll
    for (int ot = 0; ot < 4; ++ot) acc[ot] = (f32x4){0.f, 0.f, 0.f, 0.f};
    const __bf16* pa = xrb + ((((size_t)b << 10) + (mt << 4) + ln) << 8) + (quad << 3);
    const __bf16* pbm = wkb + (((w << 6) + ln) << 8) + (quad << 3);
#pragma unroll
    for (int cc = 0; cc < 8; ++cc) {
        const int cb = cc << 5;
        bf16x8 af = *(const bf16x8*)&pa[cb];
        bf16x8 bfr[4];
#pragma unroll
        for (int ot = 0; ot < 4; ++ot) bfr[ot] = *(const bf16x8*)&pbm[(ot << 12) + cb];
#pragma unroll
        for (int ot = 0; ot < 4; ++ot)
            acc[ot] = __builtin_amdgcn_mfma_f32_16x16x32_bf16(af, bfr[ot], acc[ot], 0, 0, 0);
    }
#pragma unroll
    for (int ot = 0; ot < 4; ++ot)
#pragma unroll
        for (int r = 0; r < 4; ++r) {
            int m = (mt << 4) + (quad << 2) + r;
            int h = (w << 1) + (ot >> 1);
            int d = ((ot & 1) << 4) + ln;
            kkbh[(((size_t)(b * 8 + h)) << 15) + (m << 5) + d] = (__bf16)acc[ot][r];
        }
}

// ---------------------------------------------------------------------------
// k_scores3: half-split (4 heads / block).  grid = b(2) x nchunk(256) x hp(2)
// = 1024.  Result: atomicAdd of sum-of-head-maxes into ssg[b][n].
__global__ __launch_bounds__(256) void k_scores3(const __bf16* __restrict__ xTf,
                                                 const __bf16* __restrict__ wqf,
                                                 const __bf16* __restrict__ kkbh,
                                                 float* __restrict__ ssg) {
    __shared__ __align__(16) __bf16 qs[64 * 132];
    __shared__ float smax[1024];   // [w(4)][hl(4)][n(64)]
    const int t = threadIdx.x;
    const int w = t >> 6;
    const int lane = t & 63;
    const int ln = lane & 15;
    const int quad = lane >> 4;
    const int bx = blockIdx.x;
    const int hp = bx & 1;
    const int n0 = ((bx >> 1) & 255) << 6;
    const int b = bx >> 9;

    // ---------------- q phase: wave w = ntile, o in [hp*128, hp*128+128)
    f32x4 acc[8];
#pragma unroll
    for (int ot = 0; ot < 8; ++ot) acc[ot] = (f32x4){0.f, 0.f, 0.f, 0.f};
    const __bf16* pa = xTf + ((size_t)(b * 1024 + (n0 >> 4) + w) << 12) + (lane << 3);
    const __bf16* pbm = wqf + ((size_t)(hp << 3) << 12) + (lane << 3);
#pragma unroll 2
    for (int cc = 0; cc < 8; ++cc) {
        const int cb = cc << 9;
        bf16x8 af = *(const bf16x8*)&pa[cb];
        bf16x8 bfr[8];
#pragma unroll
        for (int ot = 0; ot < 8; ++ot) bfr[ot] = *(const bf16x8*)&pbm[(ot << 12) + cb];
#pragma unroll
        for (int ot = 0; ot < 8; ++ot)
            acc[ot] = __builtin_amdgcn_mfma_f32_16x16x32_bf16(af, bfr[ot], acc[ot], 0, 0, 0);
    }
#pragma unroll
    for (int ot = 0; ot < 8; ++ot)
#pragma unroll
        for (int r = 0; r < 4; ++r)
            qs[((w << 4) + (quad << 2) + r) * 132 + (ot << 4) + ln] = (__bf16)acc[ot][r];
    __syncthreads();

    // ---------------- score phase: wave w = m quarter; 4 heads
    const f32x4 zf = {0.f, 0.f, 0.f, 0.f};
#pragma unroll
    for (int hl = 0; hl < 4; ++hl) {
        const int h = (hp << 2) + hl;
        bf16x8 qb[4];
#pragma unroll
        for (int nt = 0; nt < 4; ++nt)
            qb[nt] = *(const bf16x8*)&qs[((nt << 4) + ln) * 132 + (hl << 5) + (quad << 3)];
        const __bf16* kb_base = kkbh + ((size_t)(b * 8 + h) << 15) + (ln << 5) + (quad << 3);
        float rmx[4] = {-INFINITY, -INFINITY, -INFINITY, -INFINITY};
#pragma unroll
        for (int bi = 0; bi < 2; ++bi) {
            bf16x8 kb[8];
#pragma unroll
            for (int i = 0; i < 8; ++i)
                kb[i] = *(const bf16x8*)&kb_base[((w << 8) + ((bi * 8 + i) << 4)) << 5];
#pragma unroll
            for (int i = 0; i < 8; ++i)
#pragma unroll
                for (int nt = 0; nt < 4; ++nt) {
                    f32x4 d = __builtin_amdgcn_mfma_f32_16x16x32_bf16(kb[i], qb[nt], zf,
                                                                      0, 0, 0);
                    float t1 = fmaxf(fmaxf(d[0], d[1]), d[2]);
                    rmx[nt] = fmaxf(fmaxf(t1, d[3]), rmx[nt]);
                }
        }
#pragma unroll
        for (int nt = 0; nt < 4; ++nt) {
            rmx[nt] = fmaxf(rmx[nt], __shfl_xor(rmx[nt], 16, 64));
            rmx[nt] = fmaxf(rmx[nt], __shfl_xor(rmx[nt], 32, 64));
        }
        if (lane < 16) {
#pragma unroll
            for (int nt = 0; nt < 4; ++nt)
                smax[(w << 8) + (hl << 6) + (nt << 4) + lane] = rmx[nt];
        }
    }
    __syncthreads();
    if (t < 64) {
        float sum = 0.f;
#pragma unroll
        for (int hl = 0; hl < 4; ++hl) {
            float vv = fmaxf(fmaxf(smax[(hl << 6) + t], smax[256 + (hl << 6) + t]),
                             fmaxf(smax[512 + (hl << 6) + t], smax[768 + (hl << 6) + t]));
            sum += vv;
        }
        atomicAdd(&ssg[(b << 14) + n0 + t], sum);
    }
}

// ---------------------------------------------------------------------------
// k_epi: out[b][c][n] = A[b][c]*ssg[b][n] + B0[c].  grid = 512.
// (Kernel boundary = coherence point for the ssg atomics — keep separate.)
__global__ __launch_bounds__(256) void k_epi(const float* __restrict__ ssg,
                                             const float* __restrict__ A,
                                             const float* __restrict__ B0,
                                             float* __restrict__ out) {
    __shared__ float ss[64], sA[256], sB[256];
    const int t = threadIdx.x, bid = blockIdx.x;
    const int b = bid >> 8, n0 = (bid & 255) << 6;
    if (t < 64) ss[t] = ssg[(b << 14) + n0 + t];
    sA[t] = A[b * 256 + t];
    sB[t] = B0[t];
    __syncthreads();
#pragma unroll
    for (int i = 0; i < 16; ++i) {
        int e = t + (i << 8);
        int c = e >> 4, n4 = (e & 15) << 2;
        float4 s4 = *(const float4*)&ss[n4];
        float a = sA[c], bb = sB[c];
        float4 o4 = make_float4(fmaf(a, s4.x, bb), fmaf(a, s4.y, bb),
                                fmaf(a, s4.z, bb), fmaf(a, s4.w, bb));
        *(float4*)&out[((size_t)(b * 256 + c) << 14) + n0 + n4] = o4;
    }
}

// ---------------------------------------------------------------------------
extern "C" void kernel_launch(void* const* d_in, const int* in_sizes, int n_in,
                              void* d_out, int out_size, void* d_ws, size_t ws_size,
                              hipStream_t stream) {
    const float* x    = (const float*)d_in[0];
    const float* wq   = (const float*)d_in[1];
    const float* wk   = (const float*)d_in[2];
    const float* wsr  = (const float*)d_in[3];
    const float* sg   = (const float*)d_in[4];
    const float* sb   = (const float*)d_in[5];
    const float* smn  = (const float*)d_in[6];
    const float* svr  = (const float*)d_in[7];
    const float* wproj= (const float*)d_in[8];
    const float* pg   = (const float*)d_in[9];
    const float* pb   = (const float*)d_in[10];
    const float* pm   = (const float*)d_in[11];
    const float* pvr  = (const float*)d_in[12];
    float* out = (float*)d_out;

    char* W = (char*)d_ws;
    float*  w_A    = (float*) (W + 0);         // 512 f
    float*  w_B0   = (float*) (W + 4096);      // 256 f
    float*  w_vpart= (float*) (W + 8192);      // 64 KB (2*256*32 f)
    float*  w_ssg  = (float*) (W + 76800);     // 128 KB (2*16384 f)
    __bf16* w_wqf  = (__bf16*)(W + 212992);    // 128 KB
    __bf16* w_wkb  = (__bf16*)(W + 344064);    // 128 KB
    __bf16* w_wsrf = (__bf16*)(W + 475136);    // 2 MB
    __bf16* w_xrb  = (__bf16*)(W + 2572288);   // 512 KB
    __bf16* w_kkbh = (__bf16*)(W + 3096576);   // 1 MB
    __bf16* w_Pbf  = (__bf16*)(W + 4194304);   // 16 MB
    __bf16* w_xTf  = (__bf16*)(W + 20971520);  // 16 MB  (total 36 MB)

    k_prep<<<1632, 256, 0, stream>>>(x, wq, wk, wsr, w_wqf, w_wkb, w_wsrf,
                                     w_Pbf, w_xTf, w_vpart, w_ssg);
    k_conv1f<<<512, 256, 0, stream>>>(w_Pbf, w_wsrf, sg, sb, smn, svr, w_xrb);
    k_kmat2<<<130, 256, 0, stream>>>(w_xrb, w_wkb, w_kkbh, w_vpart, wproj,
                                     pg, pb, pm, pvr, w_A, w_B0);
    k_scores3<<<1024, 256, 0, stream>>>(w_xTf, w_wqf, w_kkbh, w_ssg);
    k_epi<<<512, 256, 0, stream>>>(w_ssg, w_A, w_B0, out);
}